// Round 1
// baseline (8913.792 us; speedup 1.0000x reference)
//
#include <hip/hip_runtime.h>
#include <math.h>

// Problem constants
#define Bb   64
#define Cc   100
#define Ff   2048
#define Tt   32
#define Hh   300
#define COMBc 2648
#define KP   2688   // COMB padded to 8*336 (336 = 21*16)
#define N4   1200   // 4 gates * H, interleaved n = 4*col + gate
#define KPP  2368   // 2048+300 padded to 148*16
#define NPP  336    // 300 padded to 7*48
#define KOP  304    // 300 padded to 19*16
#define BOSi 1

__device__ __forceinline__ float sigmf_(float x){ return 1.0f/(1.0f + expf(-x)); }

__device__ __forceinline__ void fma16_(const float4 av, const float4 bv, float acc[4][4]){
    acc[0][0] += av.x*bv.x; acc[0][1] += av.x*bv.y; acc[0][2] += av.x*bv.z; acc[0][3] += av.x*bv.w;
    acc[1][0] += av.y*bv.x; acc[1][1] += av.y*bv.y; acc[1][2] += av.y*bv.z; acc[1][3] += av.y*bv.w;
    acc[2][0] += av.z*bv.x; acc[2][1] += av.z*bv.y; acc[2][2] += av.z*bv.z; acc[2][3] += av.z*bv.w;
    acc[3][0] += av.w*bv.x; acc[3][1] += av.w*bv.y; acc[3][2] += av.w*bv.z; acc[3][3] += av.w*bv.w;
}

// ---------------------------------------------------------------------------
// Pack weights: W4p (KP x N4, gate-interleaved), Wpp ([Wcp;Whp] KPP x NPP),
// Wopp (KOP x NPP), bias4 (N4 interleaved), biasp (NPP, = bcp+bhp)
// ---------------------------------------------------------------------------
__global__ void k_pack(const float* Wi, const float* Wf, const float* Wo, const float* Wg,
                       const float* bi, const float* bf, const float* bo, const float* bg,
                       const float* Wcp, const float* Whp, const float* Wop,
                       const float* bcp, const float* bhp,
                       float* W4p, float* Wpp, float* Wopp, float* b4, float* bp)
{
    const int total = KP*N4 + KPP*NPP + KOP*NPP + N4 + NPP;
    for (int idx = blockIdx.x*256 + threadIdx.x; idx < total; idx += gridDim.x*256) {
        int i = idx;
        if (i < KP*N4) {
            int j = i / N4, n = i % N4, c = n >> 2, g = n & 3;
            const float* W = (g==0)?Wi:(g==1)?Wf:(g==2)?Wo:Wg;
            W4p[i] = (j < COMBc) ? W[j*Hh + c] : 0.0f;
            continue;
        }
        i -= KP*N4;
        if (i < KPP*NPP) {
            int j = i / NPP, n = i % NPP;
            float v = 0.0f;
            if (n < Hh) {
                if (j < Ff) v = Wcp[j*Hh + n];
                else if (j < Ff+Hh) v = Whp[(j-Ff)*Hh + n];
            }
            Wpp[i] = v;
            continue;
        }
        i -= KPP*NPP;
        if (i < KOP*NPP) {
            int j = i / NPP, n = i % NPP;
            Wopp[i] = (j < Hh && n < Hh) ? Wop[j*Hh + n] : 0.0f;
            continue;
        }
        i -= KOP*NPP;
        if (i < N4) {
            int c = i >> 2, g = i & 3;
            const float* bb = (g==0)?bi:(g==1)?bf:(g==2)?bo:bg;
            b4[i] = bb[c];
            continue;
        }
        i -= N4;
        bp[i] = (i < Hh) ? (bcp[i] + bhp[i]) : 0.0f;
    }
}

// ---------------------------------------------------------------------------
// Init: mean_enc (LDS only), e_enc, h0, c0, embedding gather E[t][j][b],
// out[:,0,:] = embedding[BOS]
// ---------------------------------------------------------------------------
__global__ void k_init(const float* enc, const int* caps, const float* emb,
                       const float* Wh0, const float* bh0,
                       const float* Wc0, const float* bc0,
                       const float* We_enc,
                       float* e_enc, float* hT, float* cst, float* E, float* out)
{
    const int b = blockIdx.x, tid = threadIdx.x;
    __shared__ float mLDS[Ff];

    // mean over channels
    for (int f = tid; f < Ff; f += 256) {
        float s = 0.0f;
        const float* p = enc + (b*Cc)*Ff + f;
        for (int c = 0; c < Cc; c++) s += p[c*Ff];
        mLDS[f] = s * (1.0f/Cc);
    }
    // e_enc: one wave per channel (interleaved)
    const int w = tid >> 6, lane = tid & 63;
    for (int c = w; c < Cc; c += 4) {
        float s = 0.0f;
        const float* p = enc + (b*Cc + c)*Ff;
        for (int k = lane; k < Ff; k += 64) s += p[k]*We_enc[k];
        for (int o = 32; o; o >>= 1) s += __shfl_xor(s, o);
        if (lane == 0) e_enc[b*Cc + c] = s;
    }
    __syncthreads();
    // h0, c0 (coalesced over hh across lanes)
    for (int hh = tid; hh < Hh; hh += 256) {
        float a1 = 0.0f, a2 = 0.0f;
        for (int f = 0; f < Ff; f++) {
            float m = mLDS[f];
            a1 += m * Wh0[f*Hh + hh];
            a2 += m * Wc0[f*Hh + hh];
        }
        hT[(0*Hh + hh)*64 + b] = tanhf(a1 + bh0[hh]);
        cst[b*Hh + hh]         = tanhf(a2 + bc0[hh]);
    }
    // embedding gather for teacher forcing: E[t][j][b], t = 0..30
    for (int idx = tid; idx < (Tt-1)*Hh; idx += 256) {
        int t = idx / Hh, j = idx % Hh;
        E[(t*Hh + j)*64 + b] = emb[(long)caps[b*Tt + t]*Hh + j];
    }
    // out[:,0,:] = embedding[BOS]
    for (int j = tid; j < Hh; j += 256)
        out[(b*Tt + 0)*Hh + j] = emb[(long)BOSi*Hh + j];
}

// ---------------------------------------------------------------------------
// Attention + context for step t (1..31). One block per batch element.
// Writes ctxT[(t-1)*Ff + f][b].
// ---------------------------------------------------------------------------
__global__ void k_attn(int t, const float* enc, const float* e_enc,
                       const float* We_hid, const float* be,
                       const float* hT, float* ctxT)
{
    const int b = blockIdx.x, tid = threadIdx.x;
    __shared__ float red[256];
    __shared__ float attn[128];

    float p = 0.0f;
    for (int j = tid; j < Hh; j += 256)
        p += hT[((t-1)*Hh + j)*64 + b] * We_hid[j];
    red[tid] = p;
    __syncthreads();
    for (int s = 128; s > 0; s >>= 1) {
        if (tid < s) red[tid] += red[tid + s];
        __syncthreads();
    }
    const float eh = red[0] + be[0];

    if (tid < 64) {
        float v0 = e_enc[b*Cc + tid] + eh;
        float v1 = (tid + 64 < Cc) ? (e_enc[b*Cc + tid + 64] + eh) : -1e30f;
        float m = fmaxf(v0, v1);
        for (int o = 32; o; o >>= 1) m = fmaxf(m, __shfl_xor(m, o));
        float e0 = expf(v0 - m);
        float e1 = (tid + 64 < Cc) ? expf(v1 - m) : 0.0f;
        float s = e0 + e1;
        for (int o = 32; o; o >>= 1) s += __shfl_xor(s, o);
        float inv = 1.0f / s;
        attn[tid] = e0 * inv;
        attn[tid + 64] = e1 * inv;
    }
    __syncthreads();

    const float* pe = enc + b*Cc*Ff;
    for (int f = tid; f < Ff; f += 256) {
        float acc = 0.0f;
        for (int c = 0; c < Cc; c++) acc += attn[c] * pe[c*Ff + f];
        ctxT[((t-1)*Ff + f)*64 + b] = acc;
    }
}

// ---------------------------------------------------------------------------
// Gate GEMM, step t: partial[ks][b][n] = comb[b][k-range] @ W4p[k-range][n]
// A is gathered on the fly: comb = [emb_prev | h_prev | ctx_t] (k-major [k][b]).
// Tile 64(M) x 48(N), micro 4x4, 192 threads, K-split 8 (chunks of 336).
// ---------------------------------------------------------------------------
__global__ __launch_bounds__(192) void k_gemm_gates(int t, const float* E, const float* hT,
                                                    const float* ctxT, const float* W4p,
                                                    float* part)
{
    const int nt = blockIdx.x, ks = blockIdx.y, tid = threadIdx.x;
    const int n0 = nt*48, tx = tid % 12, ty = tid / 12;
    __shared__ float As[16][64];
    __shared__ float Bs[16][48];
    float acc[4][4] = {};
    const int k0 = ks*336;
    const float* Esrc = E    + (t-1)*Hh*64;
    const float* hsrc = hT   + (t-1)*Hh*64;
    const float* csrc = ctxT + (t-1)*Ff*64;

    for (int kb = 0; kb < 21; kb++) {
        const int kbase = k0 + kb*16;
        for (int idx = tid; idx < 1024; idx += 192) {
            int kk = idx >> 6, bb = idx & 63, j = kbase + kk;
            float v;
            if (j < Hh)           v = Esrc[j*64 + bb];
            else if (j < 2*Hh)    v = hsrc[(j - Hh)*64 + bb];
            else if (j < COMBc)   v = csrc[(j - 2*Hh)*64 + bb];
            else                  v = 0.0f;
            As[kk][bb] = v;
        }
        for (int idx = tid; idx < 768; idx += 192) {
            int kk = idx / 48, nn = idx % 48;
            Bs[kk][nn] = W4p[(kbase + kk)*N4 + n0 + nn];
        }
        __syncthreads();
#pragma unroll
        for (int kk = 0; kk < 16; kk++) {
            float4 av = *(const float4*)&As[kk][ty*4];
            float4 bv = *(const float4*)&Bs[kk][tx*4];
            fma16_(av, bv, acc);
        }
        __syncthreads();
    }
#pragma unroll
    for (int i = 0; i < 4; i++) {
        float4 v = make_float4(acc[i][0], acc[i][1], acc[i][2], acc[i][3]);
        *(float4*)&part[(ks*64 + ty*4 + i)*N4 + n0 + tx*4] = v;
    }
}

// ---------------------------------------------------------------------------
// Reduce K-split partials + bias + LSTM cell update, step t.
// Writes c state and hT[t][col][b].
// ---------------------------------------------------------------------------
__global__ void k_lstm(int t, const float* part, const float* b4, float* cst, float* hT)
{
    const int idx = blockIdx.x*256 + threadIdx.x;   // 64*300 = 19200 exactly
    if (idx >= Bb*Hh) return;
    const int b = idx / Hh, col = idx % Hh;
    const float4* p4 = (const float4*)part;
    float4 s = ((const float4*)b4)[col];
    for (int ks = 0; ks < 8; ks++) {
        float4 v = p4[(ks*64 + b)*(N4/4) + col];
        s.x += v.x; s.y += v.y; s.z += v.z; s.w += v.w;
    }
    float ig = sigmf_(s.x), fg = sigmf_(s.y), og = sigmf_(s.z), gg = tanhf(s.w);
    float cn = fg*cst[idx] + ig*gg;
    cst[idx] = cn;
    hT[(t*Hh + col)*64 + b] = og*tanhf(cn);
}

// ---------------------------------------------------------------------------
// Deferred prediction stage A: [ctx_t | h_t] @ [Wcp;Whp], batched over all t.
// grid (7 ntiles, 31 t, 4 ksplit). Writes ppart[ks][t][n][b].
// ---------------------------------------------------------------------------
__global__ __launch_bounds__(192) void k_preda(const float* ctxT, const float* hT,
                                               const float* Wpp, float* ppart)
{
    const int nt = blockIdx.x, ti = blockIdx.y, ks = blockIdx.z, tid = threadIdx.x;
    const int n0 = nt*48, tx = tid % 12, ty = tid / 12;
    __shared__ float As[16][64];
    __shared__ float Bs[16][48];
    float acc[4][4] = {};
    const int k0 = ks*592;   // 592 = 37*16
    const float* csrc = ctxT + ti*Ff*64;
    const float* hsrc = hT + (ti+1)*Hh*64;

    for (int kb = 0; kb < 37; kb++) {
        const int kbase = k0 + kb*16;
        for (int idx = tid; idx < 1024; idx += 192) {
            int kk = idx >> 6, bb = idx & 63, j = kbase + kk;
            float v;
            if (j < Ff)          v = csrc[j*64 + bb];
            else if (j < Ff+Hh)  v = hsrc[(j - Ff)*64 + bb];
            else                 v = 0.0f;
            As[kk][bb] = v;
        }
        for (int idx = tid; idx < 768; idx += 192) {
            int kk = idx / 48, nn = idx % 48;
            Bs[kk][nn] = Wpp[(kbase + kk)*NPP + n0 + nn];
        }
        __syncthreads();
#pragma unroll
        for (int kk = 0; kk < 16; kk++) {
            float4 av = *(const float4*)&As[kk][ty*4];
            float4 bv = *(const float4*)&Bs[kk][tx*4];
            fma16_(av, bv, acc);
        }
        __syncthreads();
    }
#pragma unroll
    for (int jn = 0; jn < 4; jn++) {
        float4 v = make_float4(acc[0][jn], acc[1][jn], acc[2][jn], acc[3][jn]);
        *(float4*)&ppart[((ks*31 + ti)*NPP + n0 + tx*4 + jn)*64 + ty*4] = v;
    }
}

// Stage A2: reduce ksplit + add emb_prev + (bcp+bhp) -> tmpT[t][j(304)][b] (zero-padded)
__global__ void k_preda2(const float* ppart, const float* E, const float* bp, float* tmpT)
{
    const int idx = blockIdx.x*256 + threadIdx.x;   // 31*304*64 = 603136 exactly
    if (idx >= 31*KOP*64) return;
    const int ti = idx / (KOP*64);
    const int r = idx % (KOP*64);
    const int j = r / 64, b = r % 64;
    float v = 0.0f;
    if (j < Hh) {
        v = E[(ti*Hh + j)*64 + b] + bp[j];
        for (int ks = 0; ks < 4; ks++)
            v += ppart[((ks*31 + ti)*NPP + j)*64 + b];
    }
    tmpT[idx] = v;
}

// Stage B: out[:, t, :] = tmp @ Wop + bop. grid (7 ntiles, 31 t).
__global__ __launch_bounds__(192) void k_predb(const float* tmpT, const float* Wopp,
                                               const float* bop, float* out)
{
    const int nt = blockIdx.x, ti = blockIdx.y, tid = threadIdx.x;
    const int n0 = nt*48, tx = tid % 12, ty = tid / 12;
    __shared__ float As[16][64];
    __shared__ float Bs[16][48];
    float acc[4][4] = {};
    const float* Asrc = tmpT + ti*KOP*64;

    for (int kb = 0; kb < 19; kb++) {
        const int kbase = kb*16;
        for (int idx = tid; idx < 1024; idx += 192) {
            int kk = idx >> 6, bb = idx & 63;
            As[kk][bb] = Asrc[(kbase + kk)*64 + bb];
        }
        for (int idx = tid; idx < 768; idx += 192) {
            int kk = idx / 48, nn = idx % 48;
            Bs[kk][nn] = Wopp[(kbase + kk)*NPP + n0 + nn];
        }
        __syncthreads();
#pragma unroll
        for (int kk = 0; kk < 16; kk++) {
            float4 av = *(const float4*)&As[kk][ty*4];
            float4 bv = *(const float4*)&Bs[kk][tx*4];
            fma16_(av, bv, acc);
        }
        __syncthreads();
    }
#pragma unroll
    for (int i = 0; i < 4; i++) {
        const int bb = ty*4 + i;
#pragma unroll
        for (int j = 0; j < 4; j++) {
            const int n = n0 + tx*4 + j;
            if (n < Hh)
                out[(bb*Tt + (ti+1))*Hh + n] = acc[i][j] + bop[n];
        }
    }
}

// ---------------------------------------------------------------------------
extern "C" void kernel_launch(void* const* d_in, const int* in_sizes, int n_in,
                              void* d_out, int out_size, void* d_ws, size_t ws_size,
                              hipStream_t stream)
{
    const float* enc    = (const float*)d_in[0];
    const int*   caps   = (const int*)  d_in[1];
    const float* emb    = (const float*)d_in[2];
    const float* Wh0    = (const float*)d_in[3];
    const float* bh0    = (const float*)d_in[4];
    const float* Wc0    = (const float*)d_in[5];
    const float* bc0    = (const float*)d_in[6];
    const float* We_enc = (const float*)d_in[7];
    const float* We_hid = (const float*)d_in[8];
    const float* be     = (const float*)d_in[9];
    const float* Wi     = (const float*)d_in[10];
    const float* bi     = (const float*)d_in[11];
    const float* Wf     = (const float*)d_in[12];
    const float* bf     = (const float*)d_in[13];
    const float* Wo     = (const float*)d_in[14];
    const float* bo     = (const float*)d_in[15];
    const float* Wg     = (const float*)d_in[16];
    const float* bg     = (const float*)d_in[17];
    const float* Wcp    = (const float*)d_in[18];
    const float* bcp    = (const float*)d_in[19];
    const float* Whp    = (const float*)d_in[20];
    const float* bhp    = (const float*)d_in[21];
    const float* Wop    = (const float*)d_in[22];
    const float* bop    = (const float*)d_in[23];
    float* out = (float*)d_out;

    // Workspace carve-up (floats). Total ~53.2 MB.
    float* w = (float*)d_ws;
    float* W4p   = w; w += KP*N4;        // 3,225,600
    float* Wpp   = w; w += KPP*NPP;      //   795,648
    float* Wopp  = w; w += KOP*NPP;      //   102,144
    float* b4    = w; w += N4;
    float* bp    = w; w += NPP;
    float* e_enc = w; w += Bb*Cc;
    float* hT    = w; w += Tt*Hh*64;     // h_t for t=0..31, layout [t][col][b]
    float* ctxT  = w; w += 31*Ff*64;     // ctx_t for t=1..31, layout [t-1][f][b]
    float* E     = w; w += 31*Hh*64;     // emb_prev, layout [t][j][b]
    float* cst   = w; w += Bb*Hh;
    float* part  = w; w += 8*Bb*N4;
    float* ppart = w; w += 4*31*NPP*64;
    float* tmpT  = w; w += 31*KOP*64;
    (void)ws_size; (void)in_sizes; (void)n_in; (void)out_size;

    k_pack<<<4096, 256, 0, stream>>>(Wi, Wf, Wo, Wg, bi, bf, bo, bg,
                                     Wcp, Whp, Wop, bcp, bhp,
                                     W4p, Wpp, Wopp, b4, bp);
    k_init<<<64, 256, 0, stream>>>(enc, caps, emb, Wh0, bh0, Wc0, bc0, We_enc,
                                   e_enc, hT, cst, E, out);

    for (int t = 1; t < Tt; t++) {
        k_attn<<<64, 256, 0, stream>>>(t, enc, e_enc, We_hid, be, hT, ctxT);
        k_gemm_gates<<<dim3(25, 8), 192, 0, stream>>>(t, E, hT, ctxT, W4p, part);
        k_lstm<<<75, 256, 0, stream>>>(t, part, b4, cst, hT);
    }

    k_preda<<<dim3(7, 31, 4), 192, 0, stream>>>(ctxT, hT, Wpp, ppart);
    k_preda2<<<2356, 256, 0, stream>>>(ppart, E, bp, tmpT);
    k_predb<<<dim3(7, 31), 192, 0, stream>>>(tmpT, Wopp, bop, out);
}

// Round 2
// 3295.023 us; speedup vs baseline: 2.7052x; 2.7052x over previous
//
#include <hip/hip_runtime.h>
#include <math.h>

// Problem constants
#define Bb   64
#define Cc   100
#define Ff   2048
#define Tt   32
#define Hh   300
#define COMBc 2648
#define KP   2688   // COMB padded to 8*336 (336 = 21*16)
#define N4   1200   // 4 gates * H, interleaved n = 4*col + gate
#define KPP  2368   // 2048+300 padded to 148*16
#define NPP  336    // 300 padded to 7*48
#define KOP  304    // 300 padded to 19*16
#define NH   624    // 2*H padded to 13*48 (h0/c0 interleaved n = 2*col + g)
#define BOSi 1

__device__ __forceinline__ float sigmf_(float x){ return 1.0f/(1.0f + expf(-x)); }

__device__ __forceinline__ void fma16_(const float4 av, const float4 bv, float acc[4][4]){
    acc[0][0] += av.x*bv.x; acc[0][1] += av.x*bv.y; acc[0][2] += av.x*bv.z; acc[0][3] += av.x*bv.w;
    acc[1][0] += av.y*bv.x; acc[1][1] += av.y*bv.y; acc[1][2] += av.y*bv.z; acc[1][3] += av.y*bv.w;
    acc[2][0] += av.z*bv.x; acc[2][1] += av.z*bv.y; acc[2][2] += av.z*bv.z; acc[2][3] += av.z*bv.w;
    acc[3][0] += av.w*bv.x; acc[3][1] += av.w*bv.y; acc[3][2] += av.w*bv.z; acc[3][3] += av.w*bv.w;
}

// ---------------------------------------------------------------------------
// Pack weights:
//  W4p  (KP x N4)  gate-interleaved n=4*col+g
//  Wpp  ([Wcp;Whp] KPP x NPP)
//  Wopp (KOP x NPP)
//  Whc  ([Wh0|Wc0] Ff x NH) interleaved n=2*col+g
//  b4 (N4), bp (NPP = bcp+bhp), bhc (NH interleaved bh0/bc0)
// ---------------------------------------------------------------------------
__global__ void k_pack(const float* Wi, const float* Wf, const float* Wo, const float* Wg,
                       const float* bi, const float* bf, const float* bo, const float* bg,
                       const float* Wcp, const float* Whp, const float* Wop,
                       const float* bcp, const float* bhp,
                       const float* Wh0, const float* Wc0, const float* bh0, const float* bc0,
                       float* W4p, float* Wpp, float* Wopp, float* Whc,
                       float* b4, float* bp, float* bhc)
{
    const int total = KP*N4 + KPP*NPP + KOP*NPP + Ff*NH + N4 + NPP + NH;
    for (int idx = blockIdx.x*256 + threadIdx.x; idx < total; idx += gridDim.x*256) {
        int i = idx;
        if (i < KP*N4) {
            int j = i / N4, n = i % N4, c = n >> 2, g = n & 3;
            const float* W = (g==0)?Wi:(g==1)?Wf:(g==2)?Wo:Wg;
            W4p[i] = (j < COMBc) ? W[j*Hh + c] : 0.0f;
            continue;
        }
        i -= KP*N4;
        if (i < KPP*NPP) {
            int j = i / NPP, n = i % NPP;
            float v = 0.0f;
            if (n < Hh) {
                if (j < Ff) v = Wcp[j*Hh + n];
                else if (j < Ff+Hh) v = Whp[(j-Ff)*Hh + n];
            }
            Wpp[i] = v;
            continue;
        }
        i -= KPP*NPP;
        if (i < KOP*NPP) {
            int j = i / NPP, n = i % NPP;
            Wopp[i] = (j < Hh && n < Hh) ? Wop[j*Hh + n] : 0.0f;
            continue;
        }
        i -= KOP*NPP;
        if (i < Ff*NH) {
            int j = i / NH, n = i % NH, c = n >> 1, g = n & 1;
            Whc[i] = (c < Hh) ? (g ? Wc0[j*Hh + c] : Wh0[j*Hh + c]) : 0.0f;
            continue;
        }
        i -= Ff*NH;
        if (i < N4) {
            int c = i >> 2, g = i & 3;
            const float* bb = (g==0)?bi:(g==1)?bf:(g==2)?bo:bg;
            b4[i] = bb[c];
            continue;
        }
        i -= N4;
        if (i < NPP) {
            bp[i] = (i < Hh) ? (bcp[i] + bhp[i]) : 0.0f;
            continue;
        }
        i -= NPP;
        { int c = i >> 1, g = i & 1;
          bhc[i] = (c < Hh) ? (g ? bc0[c] : bh0[c]) : 0.0f; }
    }
}

// ---------------------------------------------------------------------------
// meanT[f][b] = mean over channels. grid (8 f-tiles, 64 b), 256 thr.
// ---------------------------------------------------------------------------
__global__ __launch_bounds__(256) void k_meanT(const float* enc, float* meanT)
{
    const int b = blockIdx.y, f = blockIdx.x*256 + threadIdx.x;
    const float* pe = enc + (b*Cc)*Ff + f;
    float s = 0.0f;
#pragma unroll 10
    for (int c = 0; c < Cc; c++) s += pe[c*Ff];
    meanT[f*64 + b] = s * (1.0f/Cc);
}

// e_enc[b][c] = dot(enc[b,c,:], We_enc). grid (25 c-groups, 64 b), wave per c.
__global__ __launch_bounds__(256) void k_eenc(const float* enc, const float* We_enc, float* e_enc)
{
    const int b = blockIdx.y;
    const int w = threadIdx.x >> 6, lane = threadIdx.x & 63;
    const int c = blockIdx.x*4 + w;
    if (c < Cc) {
        const float* p = enc + (b*Cc + c)*Ff;
        float s = 0.0f;
        for (int k = lane; k < Ff; k += 64) s += p[k]*We_enc[k];
        for (int o = 32; o; o >>= 1) s += __shfl_xor(s, o);
        if (lane == 0) e_enc[b*Cc + c] = s;
    }
}

// Embedding gather E[t][j][b], coalesced reads of emb rows.
__global__ void k_embed(const int* caps, const float* emb, float* E)
{
    const int idx = blockIdx.x*256 + threadIdx.x;
    if (idx >= (Tt-1)*Hh*Bb) return;
    const int j = idx % Hh;
    const int bt = idx / Hh;
    const int b = bt / (Tt-1), t = bt % (Tt-1);
    E[(t*Hh + j)*64 + b] = emb[(long)caps[b*Tt + t]*Hh + j];
}

// out[:,0,:] = embedding[BOS]
__global__ void k_bos(const float* emb, float* out)
{
    const int idx = blockIdx.x*256 + threadIdx.x;
    if (idx >= Bb*Hh) return;
    const int b = idx / Hh, j = idx % Hh;
    out[(b*Tt)*Hh + j] = emb[(long)BOSi*Hh + j];
}

// ---------------------------------------------------------------------------
// h0/c0 GEMM: meanT (64 x 2048, k-major) @ Whc (2048 x 624). grid (13, 8 ksplit).
// ---------------------------------------------------------------------------
__global__ __launch_bounds__(192) void k_gemm_h0(const float* meanT, const float* Whc, float* parth)
{
    const int nt = blockIdx.x, ks = blockIdx.y, tid = threadIdx.x;
    const int n0 = nt*48, tx = tid % 12, ty = tid / 12;
    __shared__ float As[16][64];
    __shared__ float Bs[16][48];
    float acc[4][4] = {};
    const int k0 = ks*256;
    for (int kb = 0; kb < 16; kb++) {
        const int kbase = k0 + kb*16;
        for (int idx = tid; idx < 1024; idx += 192) {
            int kk = idx >> 6, bb = idx & 63;
            As[kk][bb] = meanT[(kbase + kk)*64 + bb];
        }
        for (int idx = tid; idx < 768; idx += 192) {
            int kk = idx / 48, nn = idx % 48;
            Bs[kk][nn] = Whc[(kbase + kk)*NH + n0 + nn];
        }
        __syncthreads();
#pragma unroll
        for (int kk = 0; kk < 16; kk++) {
            float4 av = *(const float4*)&As[kk][ty*4];
            float4 bv = *(const float4*)&Bs[kk][tx*4];
            fma16_(av, bv, acc);
        }
        __syncthreads();
    }
#pragma unroll
    for (int i = 0; i < 4; i++)
        *(float4*)&parth[(ks*64 + ty*4 + i)*NH + n0 + tx*4]
            = make_float4(acc[i][0], acc[i][1], acc[i][2], acc[i][3]);
}

// ---------------------------------------------------------------------------
// Shared epilogue: energy + softmax for step (slot+1), h of current step in hbuf.
// Block = one b, 256 threads. Writes attnbuf[slot][b][0..127].
// ---------------------------------------------------------------------------
__device__ __forceinline__ void attn_softmax(int b, int slot, const float* e_enc,
                                             const float* We_hid, float bev,
                                             const float* hbuf, float* red, float* attnbuf)
{
    const int tid = threadIdx.x;
    float p = hbuf[tid]*We_hid[tid];
    if (tid + 256 < Hh) p += hbuf[tid+256]*We_hid[tid+256];
    red[tid] = p;
    __syncthreads();
    for (int s = 128; s > 0; s >>= 1) {
        if (tid < s) red[tid] += red[tid + s];
        __syncthreads();
    }
    const float eh = red[0] + bev;
    if (tid < 64) {
        float v0 = e_enc[b*Cc + tid] + eh;
        float v1 = (tid + 64 < Cc) ? (e_enc[b*Cc + tid + 64] + eh) : -1e30f;
        float m = fmaxf(v0, v1);
        for (int o = 32; o; o >>= 1) m = fmaxf(m, __shfl_xor(m, o));
        float e0 = expf(v0 - m);
        float e1 = (tid + 64 < Cc) ? expf(v1 - m) : 0.0f;
        float s = e0 + e1;
        for (int o = 32; o; o >>= 1) s += __shfl_xor(s, o);
        float inv = 1.0f / s;
        attnbuf[slot*8192 + b*128 + tid]      = e0 * inv;
        attnbuf[slot*8192 + b*128 + tid + 64] = e1 * inv;
    }
}

// h0/c0 epilogue + attention for step 1.
__global__ __launch_bounds__(256) void k_h0fin(const float* parth, const float* bhc,
                                               const float* e_enc, const float* We_hid,
                                               const float* be,
                                               float* hT, float* cst, float* attnbuf)
{
    const int b = blockIdx.x, tid = threadIdx.x;
    __shared__ float hbuf[Hh];
    __shared__ float red[256];
    for (int col = tid; col < Hh; col += 256) {
        float sh = bhc[2*col], sc = bhc[2*col+1];
        for (int ks = 0; ks < 8; ks++) {
            const float2 v = *(const float2*)&parth[(ks*64 + b)*NH + 2*col];
            sh += v.x; sc += v.y;
        }
        float h = tanhf(sh);
        cst[b*Hh + col] = tanhf(sc);
        hT[(0*Hh + col)*64 + b] = h;
        hbuf[col] = h;
    }
    __syncthreads();
    attn_softmax(b, 0, e_enc, We_hid, be[0], hbuf, red, attnbuf);
}

// ---------------------------------------------------------------------------
// Context for step t: ctx[b][f] = sum_c attn[c] * enc[b][c][f].
// grid (8 f-tiles, 64 b), 256 threads, one thread per f.
// ---------------------------------------------------------------------------
__global__ __launch_bounds__(256) void k_ctx(int t, const float* enc, const float* attnbuf,
                                             float* ctxT)
{
    const int b = blockIdx.y, f = blockIdx.x*256 + threadIdx.x;
    __shared__ float sA[Cc];
    if (threadIdx.x < Cc) sA[threadIdx.x] = attnbuf[(t-1)*8192 + b*128 + threadIdx.x];
    __syncthreads();
    const float* pe = enc + (b*Cc)*Ff + f;
    float acc = 0.0f;
#pragma unroll 10
    for (int c = 0; c < Cc; c++) acc += sA[c] * pe[c*Ff];
    ctxT[((t-1)*Ff + f)*64 + b] = acc;
}

// ---------------------------------------------------------------------------
// Gate GEMM, step t (unchanged from round 1).
// ---------------------------------------------------------------------------
__global__ __launch_bounds__(192) void k_gemm_gates(int t, const float* E, const float* hT,
                                                    const float* ctxT, const float* W4p,
                                                    float* part)
{
    const int nt = blockIdx.x, ks = blockIdx.y, tid = threadIdx.x;
    const int n0 = nt*48, tx = tid % 12, ty = tid / 12;
    __shared__ float As[16][64];
    __shared__ float Bs[16][48];
    float acc[4][4] = {};
    const int k0 = ks*336;
    const float* Esrc = E    + (t-1)*Hh*64;
    const float* hsrc = hT   + (t-1)*Hh*64;
    const float* csrc = ctxT + (t-1)*Ff*64;

    for (int kb = 0; kb < 21; kb++) {
        const int kbase = k0 + kb*16;
        for (int idx = tid; idx < 1024; idx += 192) {
            int kk = idx >> 6, bb = idx & 63, j = kbase + kk;
            float v;
            if (j < Hh)           v = Esrc[j*64 + bb];
            else if (j < 2*Hh)    v = hsrc[(j - Hh)*64 + bb];
            else if (j < COMBc)   v = csrc[(j - 2*Hh)*64 + bb];
            else                  v = 0.0f;
            As[kk][bb] = v;
        }
        for (int idx = tid; idx < 768; idx += 192) {
            int kk = idx / 48, nn = idx % 48;
            Bs[kk][nn] = W4p[(kbase + kk)*N4 + n0 + nn];
        }
        __syncthreads();
#pragma unroll
        for (int kk = 0; kk < 16; kk++) {
            float4 av = *(const float4*)&As[kk][ty*4];
            float4 bv = *(const float4*)&Bs[kk][tx*4];
            fma16_(av, bv, acc);
        }
        __syncthreads();
    }
#pragma unroll
    for (int i = 0; i < 4; i++) {
        float4 v = make_float4(acc[i][0], acc[i][1], acc[i][2], acc[i][3]);
        *(float4*)&part[(ks*64 + ty*4 + i)*N4 + n0 + tx*4] = v;
    }
}

// ---------------------------------------------------------------------------
// LSTM cell update + fused attention softmax for the NEXT step.
// Block = one b (grid 64), 256 threads.
// ---------------------------------------------------------------------------
__global__ __launch_bounds__(256) void k_lstm_attn(int t, const float* part, const float* b4,
                                                   const float* e_enc, const float* We_hid,
                                                   const float* be,
                                                   float* cst, float* hT, float* attnbuf)
{
    const int b = blockIdx.x, tid = threadIdx.x;
    __shared__ float hbuf[Hh];
    __shared__ float red[256];
    for (int col = tid; col < Hh; col += 256) {
        float4 s = ((const float4*)b4)[col];
        for (int ks = 0; ks < 8; ks++) {
            const float4 v = ((const float4*)part)[(ks*64 + b)*(N4/4) + col];
            s.x += v.x; s.y += v.y; s.z += v.z; s.w += v.w;
        }
        float ig = sigmf_(s.x), fg = sigmf_(s.y), og = sigmf_(s.z), gg = tanhf(s.w);
        float cn = fg*cst[b*Hh + col] + ig*gg;
        cst[b*Hh + col] = cn;
        float h = og*tanhf(cn);
        hT[(t*Hh + col)*64 + b] = h;
        hbuf[col] = h;
    }
    __syncthreads();
    attn_softmax(b, t, e_enc, We_hid, be[0], hbuf, red, attnbuf);
}

// ---------------------------------------------------------------------------
// Deferred prediction stage A: [ctx_t | h_t] @ [Wcp;Whp], batched over all t.
// ---------------------------------------------------------------------------
__global__ __launch_bounds__(192) void k_preda(const float* ctxT, const float* hT,
                                               const float* Wpp, float* ppart)
{
    const int nt = blockIdx.x, ti = blockIdx.y, ks = blockIdx.z, tid = threadIdx.x;
    const int n0 = nt*48, tx = tid % 12, ty = tid / 12;
    __shared__ float As[16][64];
    __shared__ float Bs[16][48];
    float acc[4][4] = {};
    const int k0 = ks*592;
    const float* csrc = ctxT + ti*Ff*64;
    const float* hsrc = hT + (ti+1)*Hh*64;

    for (int kb = 0; kb < 37; kb++) {
        const int kbase = k0 + kb*16;
        for (int idx = tid; idx < 1024; idx += 192) {
            int kk = idx >> 6, bb = idx & 63, j = kbase + kk;
            float v;
            if (j < Ff)          v = csrc[j*64 + bb];
            else if (j < Ff+Hh)  v = hsrc[(j - Ff)*64 + bb];
            else                 v = 0.0f;
            As[kk][bb] = v;
        }
        for (int idx = tid; idx < 768; idx += 192) {
            int kk = idx / 48, nn = idx % 48;
            Bs[kk][nn] = Wpp[(kbase + kk)*NPP + n0 + nn];
        }
        __syncthreads();
#pragma unroll
        for (int kk = 0; kk < 16; kk++) {
            float4 av = *(const float4*)&As[kk][ty*4];
            float4 bv = *(const float4*)&Bs[kk][tx*4];
            fma16_(av, bv, acc);
        }
        __syncthreads();
    }
#pragma unroll
    for (int jn = 0; jn < 4; jn++) {
        float4 v = make_float4(acc[0][jn], acc[1][jn], acc[2][jn], acc[3][jn]);
        *(float4*)&ppart[((ks*31 + ti)*NPP + n0 + tx*4 + jn)*64 + ty*4] = v;
    }
}

// Stage A2: reduce ksplit + add emb_prev + (bcp+bhp) -> tmpT[t][j(304)][b]
__global__ void k_preda2(const float* ppart, const float* E, const float* bp, float* tmpT)
{
    const int idx = blockIdx.x*256 + threadIdx.x;
    if (idx >= 31*KOP*64) return;
    const int ti = idx / (KOP*64);
    const int r = idx % (KOP*64);
    const int j = r / 64, b = r % 64;
    float v = 0.0f;
    if (j < Hh) {
        v = E[(ti*Hh + j)*64 + b] + bp[j];
        for (int ks = 0; ks < 4; ks++)
            v += ppart[((ks*31 + ti)*NPP + j)*64 + b];
    }
    tmpT[idx] = v;
}

// Stage B: out[:, t, :] = tmp @ Wop + bop. grid (7 ntiles, 31 t).
__global__ __launch_bounds__(192) void k_predb(const float* tmpT, const float* Wopp,
                                               const float* bop, float* out)
{
    const int nt = blockIdx.x, ti = blockIdx.y, tid = threadIdx.x;
    const int n0 = nt*48, tx = tid % 12, ty = tid / 12;
    __shared__ float As[16][64];
    __shared__ float Bs[16][48];
    float acc[4][4] = {};
    const float* Asrc = tmpT + ti*KOP*64;

    for (int kb = 0; kb < 19; kb++) {
        const int kbase = kb*16;
        for (int idx = tid; idx < 1024; idx += 192) {
            int kk = idx >> 6, bb = idx & 63;
            As[kk][bb] = Asrc[(kbase + kk)*64 + bb];
        }
        for (int idx = tid; idx < 768; idx += 192) {
            int kk = idx / 48, nn = idx % 48;
            Bs[kk][nn] = Wopp[(kbase + kk)*NPP + n0 + nn];
        }
        __syncthreads();
#pragma unroll
        for (int kk = 0; kk < 16; kk++) {
            float4 av = *(const float4*)&As[kk][ty*4];
            float4 bv = *(const float4*)&Bs[kk][tx*4];
            fma16_(av, bv, acc);
        }
        __syncthreads();
    }
#pragma unroll
    for (int i = 0; i < 4; i++) {
        const int bb = ty*4 + i;
#pragma unroll
        for (int j = 0; j < 4; j++) {
            const int n = n0 + tx*4 + j;
            if (n < Hh)
                out[(bb*Tt + (ti+1))*Hh + n] = acc[i][j] + bop[n];
        }
    }
}

// ---------------------------------------------------------------------------
extern "C" void kernel_launch(void* const* d_in, const int* in_sizes, int n_in,
                              void* d_out, int out_size, void* d_ws, size_t ws_size,
                              hipStream_t stream)
{
    const float* enc    = (const float*)d_in[0];
    const int*   caps   = (const int*)  d_in[1];
    const float* emb    = (const float*)d_in[2];
    const float* Wh0    = (const float*)d_in[3];
    const float* bh0    = (const float*)d_in[4];
    const float* Wc0    = (const float*)d_in[5];
    const float* bc0    = (const float*)d_in[6];
    const float* We_enc = (const float*)d_in[7];
    const float* We_hid = (const float*)d_in[8];
    const float* be     = (const float*)d_in[9];
    const float* Wi     = (const float*)d_in[10];
    const float* bi     = (const float*)d_in[11];
    const float* Wf     = (const float*)d_in[12];
    const float* bf     = (const float*)d_in[13];
    const float* Wo     = (const float*)d_in[14];
    const float* bo     = (const float*)d_in[15];
    const float* Wg     = (const float*)d_in[16];
    const float* bg     = (const float*)d_in[17];
    const float* Wcp    = (const float*)d_in[18];
    const float* bcp    = (const float*)d_in[19];
    const float* Whp    = (const float*)d_in[20];
    const float* bhp    = (const float*)d_in[21];
    const float* Wop    = (const float*)d_in[22];
    const float* bop    = (const float*)d_in[23];
    float* out = (float*)d_out;

    // Workspace carve-up (floats).
    float* w = (float*)d_ws;
    float* W4p     = w; w += KP*N4;        // 3,225,600
    float* Wpp     = w; w += KPP*NPP;      //   795,648
    float* Wopp    = w; w += KOP*NPP;      //   102,144
    float* b4      = w; w += N4;
    float* bp      = w; w += NPP;
    float* bhc     = w; w += NH;
    float* e_enc   = w; w += Bb*Cc;
    float* hT      = w; w += Tt*Hh*64;     // h_t, t=0..31, [t][col][b]
    float* ctxT    = w; w += 31*Ff*64;     // ctx_t, t=1..31, [t-1][f][b]
    float* E       = w; w += 31*Hh*64;     // emb_prev, [t][j][b]
    float* cst     = w; w += Bb*Hh;
    float* attnbuf = w; w += 32*64*128;    // attn for step slot+1, [slot][b][c]
    float* part    = w; w += 8*Bb*N4;
    float* ppart   = w; w += 4*31*NPP*64;
    float* tmpT    = w; w += 31*KOP*64;
    // init-phase aliases (consumed before their hosts are written)
    float* Whc   = ppart;   // 2048*624 = 1,277,952 <= 2,666,496
    float* meanT = tmpT;    // 2048*64  =   131,072 <=   603,136
    float* parth = part;    // 8*64*624 =   319,488 <=   614,400
    (void)ws_size; (void)in_sizes; (void)n_in; (void)out_size;

    k_pack<<<4096, 256, 0, stream>>>(Wi, Wf, Wo, Wg, bi, bf, bo, bg,
                                     Wcp, Whp, Wop, bcp, bhp,
                                     Wh0, Wc0, bh0, bc0,
                                     W4p, Wpp, Wopp, Whc, b4, bp, bhc);
    k_meanT<<<dim3(8, 64), 256, 0, stream>>>(enc, meanT);
    k_eenc <<<dim3(25, 64), 256, 0, stream>>>(enc, We_enc, e_enc);
    k_embed<<<2325, 256, 0, stream>>>(caps, emb, E);
    k_bos  <<<75, 256, 0, stream>>>(emb, out);
    k_gemm_h0<<<dim3(13, 8), 192, 0, stream>>>(meanT, Whc, parth);
    k_h0fin<<<64, 256, 0, stream>>>(parth, bhc, e_enc, We_hid, be, hT, cst, attnbuf);

    for (int t = 1; t < Tt; t++) {
        k_ctx<<<dim3(8, 64), 256, 0, stream>>>(t, enc, attnbuf, ctxT);
        k_gemm_gates<<<dim3(25, 8), 192, 0, stream>>>(t, E, hT, ctxT, W4p, part);
        k_lstm_attn<<<64, 256, 0, stream>>>(t, part, b4, e_enc, We_hid, be, cst, hT, attnbuf);
    }

    k_preda<<<dim3(7, 31, 4), 192, 0, stream>>>(ctxT, hT, Wpp, ppart);
    k_preda2<<<2356, 256, 0, stream>>>(ppart, E, bp, tmpT);
    k_predb<<<dim3(7, 31), 192, 0, stream>>>(tmpT, Wopp, bop, out);
}